// Round 2
// baseline (27546.124 us; speedup 1.0000x reference)
//
#include <hip/hip_runtime.h>
#include <hip/hip_bf16.h>
#include <stdint.h>

// LSTM_48601849922171 — 2-layer LSTM (B=8, T=2048, D_IN=256, H=512).
// Inputs/outputs are FP32 (confirmed: round-1 absmax 2063.926 = 0x4500FECD,
// i.e. harness read our packed bf16 pairs as fp32). Internal compute: bf16
// MFMA (threshold is 8 x bf16 eps), fp32 accumulation/epilogues.
//
// Pipeline:
//   cvt  x4: w0_w,u0_w,w1_w,u1_w fp32 -> bf16 in ws
//   K1: gemm_proj  wx0 = x(bf16-cvt) @ w0_w^T (+w0_b fp32)   -> wx bf16
//   K2: lstm_rec   layer-0 recurrence -> h1seq(bf16) + hh/cc(fp32)
//   K3: gemm_proj  wx1 = h1seq @ w1_w^T (+w1_b)
//   K4: lstm_rec   layer-1 recurrence -> d_out h2 (fp32) + hh/cc
//
// lstm_rec: persistent 16 blocks x 256 thr; U held in registers as MFMA
// A-frags (128 VGPR/thread); D[g_row][batch] = U*h^T; per-step cross-block
// sync via monotonic counters + agent fences.
//
// Workspace (~135.1 MB):
//   [0,8K) cnt0  [8K,16K) cnt1
//   64K:       Wb0 bf16 1MB | Ub0 2MB | Wb1 2MB | Ub1 2MB
//   7405568:   wx   [2048][8][2048] bf16  (64MB, reused)
//   74514432:  h1s  [2048][16][512] bf16  (32MB; rows 8..15 pad)
//   108068864: h2s  [2048][16][512] bf16  (32MB)

typedef __hip_bfloat16 bf16;
typedef float  floatx4 __attribute__((ext_vector_type(4)));
typedef short  short8  __attribute__((ext_vector_type(8)));
typedef short  short4v __attribute__((ext_vector_type(4)));

#define T_STEPS 2048
#define NB_REC  16
#define HH_OFF  8388608   // 8*2048*512
#define CC_OFF  8396800   // HH_OFF + 2*8*512

static __device__ __forceinline__ float bs2f(short s) {
  union { unsigned int u; float f; } c;
  c.u = ((unsigned int)(unsigned short)s) << 16;
  return c.f;
}
static __device__ __forceinline__ short f2bs(float x) {
  union { bf16 h; short s; } u;
  u.h = __float2bfloat16(x);
  return u.s;
}
static __device__ __forceinline__ float sigm(float x) {
  x = fminf(fmaxf(x, -30.f), 30.f);
  return 1.f / (1.f + __expf(-x));
}
static __device__ __forceinline__ float tanhf_(float x) {
  x = fminf(fmaxf(x, -15.f), 15.f);
  float e = __expf(2.f * x);
  return (e - 1.f) / (e + 1.f);
}
static __device__ __forceinline__ floatx4 mfma_bf16(short8 a, short8 b, floatx4 c) {
  return __builtin_amdgcn_mfma_f32_16x16x32_bf16(a, b, c, 0, 0, 0);
}

// fp32 -> bf16 elementwise (n multiple of 4)
__global__ __launch_bounds__(256)
void cvt_f32_bf16(const float* __restrict__ src, bf16* __restrict__ dst, int n) {
  int i = (blockIdx.x * 256 + threadIdx.x) * 4;
  if (i < n) {
    floatx4 v = *reinterpret_cast<const floatx4*>(src + i);
    short4v o;
    #pragma unroll
    for (int r = 0; r < 4; ++r) o[r] = f2bs(v[r]);
    *reinterpret_cast<short4v*>(dst + i) = o;
  }
}

// ---------------------------------------------------------------------------
// out[m][n] = sum_k A[m][k]*W[n][k] + bias[n], m = t*8+b, out [16384][2048] bf16.
// A row base = (m&7)*strideB + (m>>3)*strideT (element stride). A is fp32 (Af)
// or bf16 (Ab) — exactly one non-null. W pre-converted bf16 [n][K]. bias fp32.
// Block 256 thr; wave tile M=16 x N=64; grid (1024, 8).
// ---------------------------------------------------------------------------
__global__ __launch_bounds__(256)
void gemm_proj(const float* __restrict__ Af, const bf16* __restrict__ Ab,
               const bf16* __restrict__ W, const float* __restrict__ bias,
               bf16* __restrict__ out, int K, int strideB, int strideT)
{
  const int lane  = threadIdx.x & 63;
  const int wave  = threadIdx.x >> 6;
  const int q     = lane >> 4;
  const int c     = lane & 15;
  const int mtile = blockIdx.x;
  const int nbase = blockIdx.y * 256 + wave * 64;
  const int m     = mtile * 16 + c;

  const long abase = (long)(m & 7) * strideB + (long)(m >> 3) * strideT + q * 8;
  const bf16* W0 = W + (long)(nbase +  0 + c) * K + q * 8;
  const bf16* W1 = W + (long)(nbase + 16 + c) * K + q * 8;
  const bf16* W2 = W + (long)(nbase + 32 + c) * K + q * 8;
  const bf16* W3 = W + (long)(nbase + 48 + c) * K + q * 8;

  floatx4 acc0 = {0.f, 0.f, 0.f, 0.f};
  floatx4 acc1 = acc0, acc2 = acc0, acc3 = acc0;
  const int nk = K >> 5;
  for (int kt = 0; kt < nk; ++kt) {
    short8 a;
    if (Af != nullptr) {
      floatx4 lo = *reinterpret_cast<const floatx4*>(Af + abase + kt * 32);
      floatx4 hi = *reinterpret_cast<const floatx4*>(Af + abase + kt * 32 + 4);
      #pragma unroll
      for (int r = 0; r < 4; ++r) { a[r] = f2bs(lo[r]); a[4 + r] = f2bs(hi[r]); }
    } else {
      a = *reinterpret_cast<const short8*>(Ab + abase + kt * 32);
    }
    short8 b0 = *reinterpret_cast<const short8*>(W0 + kt * 32);
    short8 b1 = *reinterpret_cast<const short8*>(W1 + kt * 32);
    short8 b2 = *reinterpret_cast<const short8*>(W2 + kt * 32);
    short8 b3 = *reinterpret_cast<const short8*>(W3 + kt * 32);
    acc0 = mfma_bf16(a, b0, acc0);
    acc1 = mfma_bf16(a, b1, acc1);
    acc2 = mfma_bf16(a, b2, acc2);
    acc3 = mfma_bf16(a, b3, acc3);
  }

  floatx4 accs[4] = {acc0, acc1, acc2, acc3};
  #pragma unroll
  for (int nt = 0; nt < 4; ++nt) {
    const int n = nbase + nt * 16 + c;
    const float bv = bias[n];
    #pragma unroll
    for (int r = 0; r < 4; ++r) {
      const int mrow = mtile * 16 + q * 4 + r;
      out[(long)mrow * 2048 + n] = __float2bfloat16(accs[nt][r] + bv);
    }
  }
}

// ---------------------------------------------------------------------------
// Persistent recurrence. 16 blocks x 256 thr. Wave owns 8 h-cols jbase..+8:
//   A-tile0 rows = {i[j..], f[j..]}, A-tile1 rows = {g[j..], o[j..]}
// D[m=q*4+r][n=lane&15]: n = batch col. f/o rows (m=8..15) live in quads 2,3;
// shfl_xor(.,32) pairs them with i/g in quads 0,1. hseq[t][16][512] bf16
// (rows 8..15 pad). Outputs written fp32.
// ---------------------------------------------------------------------------
__global__ __launch_bounds__(256)
void lstm_rec(const bf16* __restrict__ wx, const bf16* __restrict__ U,
              const float* __restrict__ ub, bf16* __restrict__ hseq,
              float* __restrict__ hout, float* __restrict__ hh,
              float* __restrict__ cc, unsigned int* __restrict__ cnt)
{
  const int lane  = threadIdx.x & 63;
  const int wave  = threadIdx.x >> 6;
  const int q     = lane >> 4;
  const int b     = lane & 15;
  const int jbase = blockIdx.x * 32 + wave * 8;

  // Preload recurrent weights as A-frags (2 M-tiles x 16 k-frags = 128 VGPR).
  short8 a0[16], a1[16];
  {
    const int row0 = (b < 8) ? (jbase + b) : (512 + jbase + b - 8);           // i | f
    const int row1 = (b < 8) ? (1024 + jbase + b) : (1536 + jbase + b - 8);   // g | o
    const bf16* U0 = U + (long)row0 * 512 + q * 8;
    const bf16* U1 = U + (long)row1 * 512 + q * 8;
    #pragma unroll
    for (int kt = 0; kt < 16; ++kt) {
      a0[kt] = *reinterpret_cast<const short8*>(U0 + kt * 32);
      a1[kt] = *reinterpret_cast<const short8*>(U1 + kt * 32);
    }
  }

  const int jj = jbase + (q & 1) * 4;   // epilogue j-range (meaningful for q<2)
  float ubi[4], ubf[4], ubg[4], ubo[4];
  #pragma unroll
  for (int r = 0; r < 4; ++r) {
    ubi[r] = ub[        jj + r];
    ubf[r] = ub[ 512 + jj + r];
    ubg[r] = ub[1024 + jj + r];
    ubo[r] = ub[1536 + jj + r];
  }

  float cst[4] = {0.f, 0.f, 0.f, 0.f};

  for (int t = 0; t < T_STEPS; ++t) {
    floatx4 acc0 = {0.f, 0.f, 0.f, 0.f};
    floatx4 acc1 = {0.f, 0.f, 0.f, 0.f};

    if (t > 0) {
      if (threadIdx.x == 0) {
        int guard = 0;
        while (__hip_atomic_load(cnt + (t - 1), __ATOMIC_RELAXED,
                                 __HIP_MEMORY_SCOPE_AGENT) < NB_REC) {
          __builtin_amdgcn_s_sleep(2);
          if (++guard > (1 << 24)) break;   // bail instead of hanging forever
        }
      }
      __syncthreads();
      __builtin_amdgcn_fence(__ATOMIC_ACQUIRE, "agent");

      const bf16* hp = hseq + (long)(t - 1) * 8192 + b * 512 + q * 8;
      #pragma unroll
      for (int kt = 0; kt < 16; ++kt) {
        short8 hb = *reinterpret_cast<const short8*>(hp + kt * 32);
        acc0 = mfma_bf16(a0[kt], hb, acc0);
        acc1 = mfma_bf16(a1[kt], hb, acc1);
      }
    }

    // Precomputed input projection (b>=8 lanes read b&7; results discarded).
    const bf16* wxp = wx + (long)t * 16384 + (b & 7) * 2048 + jj;
    float wxi[4], wxf[4], wxg[4], wxo[4];
    {
      short4v vi = *reinterpret_cast<const short4v*>(wxp);
      short4v vf = *reinterpret_cast<const short4v*>(wxp + 512);
      short4v vg = *reinterpret_cast<const short4v*>(wxp + 1024);
      short4v vo = *reinterpret_cast<const short4v*>(wxp + 1536);
      #pragma unroll
      for (int r = 0; r < 4; ++r) {
        wxi[r] = bs2f(vi[r]); wxf[r] = bs2f(vf[r]);
        wxg[r] = bs2f(vg[r]); wxo[r] = bs2f(vo[r]);
      }
    }

    // Pair i<->f and g<->o across lane^32 (all lanes execute the shfl).
    float fsh[4], osh[4];
    #pragma unroll
    for (int r = 0; r < 4; ++r) {
      fsh[r] = __shfl_xor(acc0[r], 32, 64);
      osh[r] = __shfl_xor(acc1[r], 32, 64);
    }

    if (q < 2) {
      short4v hp4;
      floatx4  hf4, cf4;
      #pragma unroll
      for (int r = 0; r < 4; ++r) {
        const float pi = acc0[r] + wxi[r] + ubi[r];
        const float pf = fsh[r]  + wxf[r] + ubf[r];
        const float pg = acc1[r] + wxg[r] + ubg[r];
        const float po = osh[r]  + wxo[r] + ubo[r];
        const float it = sigm(pi);
        const float ft = sigm(pf);
        const float gt = tanhf_(pg);
        const float ot = sigm(po);
        const float cv = ft * cst[r] + it * gt;
        cst[r] = cv;
        const float hv = ot * fmaxf(cv, 0.f);   // custom nonlinearity: relu(c)
        hf4[r] = hv;
        cf4[r] = cv;
        hp4[r] = f2bs(hv);
      }
      *reinterpret_cast<short4v*>(hseq + (long)t * 8192 + b * 512 + jj) = hp4;
      if (hout != nullptr && b < 8) {          // layer-1: h2 -> d_out [b][t][j] fp32
        *reinterpret_cast<floatx4*>(hout + (long)b * 1048576 + (long)t * 512 + jj) = hf4;
      }
      if (t == T_STEPS - 1 && b < 8) {         // final h/c states fp32
        *reinterpret_cast<floatx4*>(hh + b * 512 + jj) = hf4;
        *reinterpret_cast<floatx4*>(cc + b * 512 + jj) = cf4;
      }
    }

    __builtin_amdgcn_fence(__ATOMIC_RELEASE, "agent");
    __syncthreads();
    if (threadIdx.x == 0) {
      __hip_atomic_fetch_add(cnt + t, 1u, __ATOMIC_RELEASE, __HIP_MEMORY_SCOPE_AGENT);
    }
  }
}

extern "C" void kernel_launch(void* const* d_in, const int* in_sizes, int n_in,
                              void* d_out, int out_size, void* d_ws, size_t ws_size,
                              hipStream_t stream) {
  (void)in_sizes; (void)n_in; (void)out_size; (void)ws_size;
  const float* x   = (const float*)d_in[0];
  const float* w0w = (const float*)d_in[1];
  const float* w0b = (const float*)d_in[2];
  const float* u0w = (const float*)d_in[3];
  const float* u0b = (const float*)d_in[4];
  const float* w1w = (const float*)d_in[5];
  const float* w1b = (const float*)d_in[6];
  const float* u1w = (const float*)d_in[7];
  const float* u1b = (const float*)d_in[8];
  float* out = (float*)d_out;

  char* ws = (char*)d_ws;
  unsigned int* cnt0 = (unsigned int*)ws;
  unsigned int* cnt1 = (unsigned int*)(ws + 8192);
  bf16* Wb0 = (bf16*)(ws + 65536);
  bf16* Ub0 = (bf16*)(ws + 65536 + (size_t)1048576);
  bf16* Wb1 = (bf16*)(ws + 65536 + (size_t)3145728);
  bf16* Ub1 = (bf16*)(ws + 65536 + (size_t)5242880);
  bf16* wx  = (bf16*)(ws + 7405568);
  bf16* h1s = (bf16*)(ws + 7405568 + (size_t)67108864);
  bf16* h2s = (bf16*)(ws + 7405568 + (size_t)67108864 + (size_t)33554432);

  hipMemsetAsync(ws, 0, 16384, stream);   // zero both counter arrays

  // Weight conversions fp32 -> bf16.
  cvt_f32_bf16<<<512,  256, 0, stream>>>(w0w, Wb0, 524288);
  cvt_f32_bf16<<<1024, 256, 0, stream>>>(u0w, Ub0, 1048576);
  cvt_f32_bf16<<<1024, 256, 0, stream>>>(w1w, Wb1, 1048576);
  cvt_f32_bf16<<<1024, 256, 0, stream>>>(u1w, Ub1, 1048576);

  dim3 gg(1024, 8, 1);
  // Layer 0 input projection: A = x[b][t][d] fp32, strideB = T*D_IN, strideT = D_IN.
  gemm_proj<<<gg, 256, 0, stream>>>(x, nullptr, Wb0, w0b, wx, 256, 2048 * 256, 256);
  // Layer 0 recurrence.
  lstm_rec<<<NB_REC, 256, 0, stream>>>(wx, Ub0, u0b, h1s, nullptr,
                                       out + HH_OFF, out + CC_OFF, cnt0);
  // Layer 1 input projection: A = h1s[t][16][512] bf16, strideB = 512, strideT = 8192.
  gemm_proj<<<gg, 256, 0, stream>>>(nullptr, h1s, Wb1, w1b, wx, 512, 512, 8192);
  // Layer 1 recurrence (writes h2 fp32 to d_out).
  lstm_rec<<<NB_REC, 256, 0, stream>>>(wx, Ub1, u1b, h2s, out,
                                       out + HH_OFF + 4096, out + CC_OFF + 4096, cnt1);
}

// Round 3
// 22596.732 us; speedup vs baseline: 1.2190x; 1.2190x over previous
//
#include <hip/hip_runtime.h>
#include <hip/hip_bf16.h>
#include <stdint.h>

// LSTM_48601849922171 — 2-layer LSTM (B=8, T=2048, D_IN=256, H=512), fp32 I/O,
// bf16 MFMA compute.
//
// Round 3 change: removed agent-scope fences (they lower to bulk L2
// writeback/invalidate per step = the 6.8us/step cost). Cross-block h + flag
// traffic now goes through relaxed agent-scope atomics (sc0 sc1 -> coherent
// L3/Infinity Cache). Release ordering = __syncthreads() vmcnt drain before
// the flag store; acquire = sc0sc1 loads (no stale L1/L2 possible).
//
// Pipeline:
//   cvt x4 (weights fp32->bf16) ; K1 gemm_proj wx0 ; K2 lstm_rec L0 ;
//   K3 gemm_proj wx1 ; K4 lstm_rec L1 -> d_out.
//
// Workspace (~135.3 MB):
//   [0,128K)        flags0[2048][16] u32 (memset 0; sentinel 0x5D5D5D5D)
//   [128K,256K)     flags1
//   262144:  Wb0 1MB | Ub0 2MB | Wb1 2MB | Ub1 2MB
//   7602176: wx  [2048][8][2048] bf16 (64MB, reused both layers)
//   74711040:  h1s [2048][16][512] bf16 (32MB; rows 8..15 pad)
//   108265472: h2s [2048][16][512] bf16 (32MB)

typedef __hip_bfloat16 bf16;
typedef float  floatx4 __attribute__((ext_vector_type(4)));
typedef short  short8  __attribute__((ext_vector_type(8)));
typedef short  short4v __attribute__((ext_vector_type(4)));

#define T_STEPS  2048
#define NB_REC   16
#define SENTINEL 0x5D5D5D5Du
#define HH_OFF   8388608   // 8*2048*512
#define CC_OFF   8396800   // HH_OFF + 2*8*512

static __device__ __forceinline__ float bs2f(short s) {
  union { unsigned int u; float f; } c;
  c.u = ((unsigned int)(unsigned short)s) << 16;
  return c.f;
}
static __device__ __forceinline__ short f2bs(float x) {
  union { bf16 h; short s; } u;
  u.h = __float2bfloat16(x);
  return u.s;
}
static __device__ __forceinline__ float sigm(float x) {
  x = fminf(fmaxf(x, -30.f), 30.f);
  return 1.f / (1.f + __expf(-x));
}
static __device__ __forceinline__ float tanhf_(float x) {
  x = fminf(fmaxf(x, -15.f), 15.f);
  float e = __expf(2.f * x);
  return (e - 1.f) / (e + 1.f);
}
static __device__ __forceinline__ floatx4 mfma_bf16(short8 a, short8 b, floatx4 c) {
  return __builtin_amdgcn_mfma_f32_16x16x32_bf16(a, b, c, 0, 0, 0);
}

// fp32 -> bf16 elementwise (n multiple of 4)
__global__ __launch_bounds__(256)
void cvt_f32_bf16(const float* __restrict__ src, bf16* __restrict__ dst, int n) {
  int i = (blockIdx.x * 256 + threadIdx.x) * 4;
  if (i < n) {
    floatx4 v = *reinterpret_cast<const floatx4*>(src + i);
    short4v o;
    #pragma unroll
    for (int r = 0; r < 4; ++r) o[r] = f2bs(v[r]);
    *reinterpret_cast<short4v*>(dst + i) = o;
  }
}

// ---------------------------------------------------------------------------
// out[m][n] = sum_k A[m][k]*W[n][k] + bias[n], m = t*8+b, out [16384][2048] bf16.
// A row base = (m&7)*strideB + (m>>3)*strideT. Af fp32 xor Ab bf16. W bf16 [n][K].
// Block 256 thr; wave tile M=16 x N=64; grid (1024, 8).
// ---------------------------------------------------------------------------
__global__ __launch_bounds__(256)
void gemm_proj(const float* __restrict__ Af, const bf16* __restrict__ Ab,
               const bf16* __restrict__ W, const float* __restrict__ bias,
               bf16* __restrict__ out, int K, int strideB, int strideT)
{
  const int lane  = threadIdx.x & 63;
  const int wave  = threadIdx.x >> 6;
  const int q     = lane >> 4;
  const int c     = lane & 15;
  const int mtile = blockIdx.x;
  const int nbase = blockIdx.y * 256 + wave * 64;
  const int m     = mtile * 16 + c;

  const long abase = (long)(m & 7) * strideB + (long)(m >> 3) * strideT + q * 8;
  const bf16* W0 = W + (long)(nbase +  0 + c) * K + q * 8;
  const bf16* W1 = W + (long)(nbase + 16 + c) * K + q * 8;
  const bf16* W2 = W + (long)(nbase + 32 + c) * K + q * 8;
  const bf16* W3 = W + (long)(nbase + 48 + c) * K + q * 8;

  floatx4 acc0 = {0.f, 0.f, 0.f, 0.f};
  floatx4 acc1 = acc0, acc2 = acc0, acc3 = acc0;
  const int nk = K >> 5;
  for (int kt = 0; kt < nk; ++kt) {
    short8 a;
    if (Af != nullptr) {
      floatx4 lo = *reinterpret_cast<const floatx4*>(Af + abase + kt * 32);
      floatx4 hi = *reinterpret_cast<const floatx4*>(Af + abase + kt * 32 + 4);
      #pragma unroll
      for (int r = 0; r < 4; ++r) { a[r] = f2bs(lo[r]); a[4 + r] = f2bs(hi[r]); }
    } else {
      a = *reinterpret_cast<const short8*>(Ab + abase + kt * 32);
    }
    short8 b0 = *reinterpret_cast<const short8*>(W0 + kt * 32);
    short8 b1 = *reinterpret_cast<const short8*>(W1 + kt * 32);
    short8 b2 = *reinterpret_cast<const short8*>(W2 + kt * 32);
    short8 b3 = *reinterpret_cast<const short8*>(W3 + kt * 32);
    acc0 = mfma_bf16(a, b0, acc0);
    acc1 = mfma_bf16(a, b1, acc1);
    acc2 = mfma_bf16(a, b2, acc2);
    acc3 = mfma_bf16(a, b3, acc3);
  }

  floatx4 accs[4] = {acc0, acc1, acc2, acc3};
  #pragma unroll
  for (int nt = 0; nt < 4; ++nt) {
    const int n = nbase + nt * 16 + c;
    const float bv = bias[n];
    #pragma unroll
    for (int r = 0; r < 4; ++r) {
      const int mrow = mtile * 16 + q * 4 + r;
      out[(long)mrow * 2048 + n] = __float2bfloat16(accs[nt][r] + bv);
    }
  }
}

// ---------------------------------------------------------------------------
// Persistent recurrence, 16 blocks x 256 thr, fence-free.
// Wave owns 8 h-cols: A-tile0 rows {i,f}, A-tile1 rows {g,o};
// D[m=q*4+r][n=b]: f/o rows in quads 2,3 paired via shfl_xor(.,32).
// h communicated via relaxed AGENT atomics (sc0 sc1 -> coherent L3).
// Per-step per-block sentinel flags; consumers (threads 0..15) spin.
// ---------------------------------------------------------------------------
__global__ __launch_bounds__(256)
void lstm_rec(const bf16* __restrict__ wx, const bf16* __restrict__ U,
              const float* __restrict__ ub, bf16* __restrict__ hseq,
              float* __restrict__ hout, float* __restrict__ hh,
              float* __restrict__ cc, unsigned int* __restrict__ flags)
{
  const int lane  = threadIdx.x & 63;
  const int wave  = threadIdx.x >> 6;
  const int q     = lane >> 4;
  const int b     = lane & 15;
  const int jbase = blockIdx.x * 32 + wave * 8;

  // Preload recurrent weights as A-frags (2 M-tiles x 16 k-frags).
  short8 a0[16], a1[16];
  {
    const int row0 = (b < 8) ? (jbase + b) : (512 + jbase + b - 8);           // i | f
    const int row1 = (b < 8) ? (1024 + jbase + b) : (1536 + jbase + b - 8);   // g | o
    const bf16* U0 = U + (long)row0 * 512 + q * 8;
    const bf16* U1 = U + (long)row1 * 512 + q * 8;
    #pragma unroll
    for (int kt = 0; kt < 16; ++kt) {
      a0[kt] = *reinterpret_cast<const short8*>(U0 + kt * 32);
      a1[kt] = *reinterpret_cast<const short8*>(U1 + kt * 32);
    }
  }

  const int jj = jbase + (q & 1) * 4;   // epilogue j-range (meaningful for q<2)
  float ubi[4], ubf[4], ubg[4], ubo[4];
  #pragma unroll
  for (int r = 0; r < 4; ++r) {
    ubi[r] = ub[        jj + r];
    ubf[r] = ub[ 512 + jj + r];
    ubg[r] = ub[1024 + jj + r];
    ubo[r] = ub[1536 + jj + r];
  }

  float cst[4] = {0.f, 0.f, 0.f, 0.f};

  for (int t = 0; t < T_STEPS; ++t) {
    // Prefetch this step's input projection (plain cached loads; written by a
    // previous dispatch so implicit kernel-start acquire covers coherence).
    const bf16* wxp = wx + (long)t * 16384 + (b & 7) * 2048 + jj;
    short4v vi = *reinterpret_cast<const short4v*>(wxp);
    short4v vf = *reinterpret_cast<const short4v*>(wxp + 512);
    short4v vg = *reinterpret_cast<const short4v*>(wxp + 1024);
    short4v vo = *reinterpret_cast<const short4v*>(wxp + 1536);

    floatx4 acc0 = {0.f, 0.f, 0.f, 0.f};
    floatx4 acc1 = {0.f, 0.f, 0.f, 0.f};

    if (t > 0) {
      // Wait for all 16 producer blocks of step t-1 (one flag each).
      if (threadIdx.x < 16) {
        const unsigned int* fp = flags + (unsigned)(t - 1) * 16 + threadIdx.x;
        int guard = 0;
        while (__hip_atomic_load(fp, __ATOMIC_RELAXED,
                                 __HIP_MEMORY_SCOPE_AGENT) != SENTINEL) {
          __builtin_amdgcn_s_sleep(1);
          if (++guard > (1 << 24)) break;   // bail instead of hanging
        }
      }
      __syncthreads();

      // h(t-1) via coherent (sc0 sc1) loads — never stale, no fence needed.
      const bf16* hp = hseq + (long)(t - 1) * 8192 + b * 512 + q * 8;
      unsigned long long hlo[16], hhi[16];
      #pragma unroll
      for (int kt = 0; kt < 16; ++kt) {
        hlo[kt] = __hip_atomic_load(
            reinterpret_cast<const unsigned long long*>(hp + kt * 32),
            __ATOMIC_RELAXED, __HIP_MEMORY_SCOPE_AGENT);
        hhi[kt] = __hip_atomic_load(
            reinterpret_cast<const unsigned long long*>(hp + kt * 32 + 4),
            __ATOMIC_RELAXED, __HIP_MEMORY_SCOPE_AGENT);
      }
      #pragma unroll
      for (int kt = 0; kt < 16; ++kt) {
        union { unsigned long long u[2]; short8 v; } pk;
        pk.u[0] = hlo[kt]; pk.u[1] = hhi[kt];
        acc0 = mfma_bf16(a0[kt], pk.v, acc0);
        acc1 = mfma_bf16(a1[kt], pk.v, acc1);
      }
    }

    float wxi[4], wxf[4], wxg[4], wxo[4];
    #pragma unroll
    for (int r = 0; r < 4; ++r) {
      wxi[r] = bs2f(vi[r]); wxf[r] = bs2f(vf[r]);
      wxg[r] = bs2f(vg[r]); wxo[r] = bs2f(vo[r]);
    }

    // Pair i<->f and g<->o across lane^32 (all lanes execute the shfl).
    float fsh[4], osh[4];
    #pragma unroll
    for (int r = 0; r < 4; ++r) {
      fsh[r] = __shfl_xor(acc0[r], 32, 64);
      osh[r] = __shfl_xor(acc1[r], 32, 64);
    }

    if (q < 2) {
      short4v hp4;
      floatx4  hf4, cf4;
      #pragma unroll
      for (int r = 0; r < 4; ++r) {
        const float pi = acc0[r] + wxi[r] + ubi[r];
        const float pf = fsh[r]  + wxf[r] + ubf[r];
        const float pg = acc1[r] + wxg[r] + ubg[r];
        const float po = osh[r]  + wxo[r] + ubo[r];
        const float it = sigm(pi);
        const float ft = sigm(pf);
        const float gt = tanhf_(pg);
        const float ot = sigm(po);
        const float cv = ft * cst[r] + it * gt;
        cst[r] = cv;
        const float hv = ot * fmaxf(cv, 0.f);   // custom nonlinearity: relu(c)
        hf4[r] = hv;
        cf4[r] = cv;
        hp4[r] = f2bs(hv);
      }
      // h -> coherent point (sc0 sc1), 8B packed.
      union { short4v v; unsigned long long u; } pk; pk.v = hp4;
      __hip_atomic_store(
          reinterpret_cast<unsigned long long*>(hseq + (long)t * 8192 + b * 512 + jj),
          pk.u, __ATOMIC_RELAXED, __HIP_MEMORY_SCOPE_AGENT);
      if (hout != nullptr && b < 8) {          // layer-1: h2 -> d_out fp32
        *reinterpret_cast<floatx4*>(hout + (long)b * 1048576 + (long)t * 512 + jj) = hf4;
      }
      if (t == T_STEPS - 1 && b < 8) {         // final h/c states fp32
        *reinterpret_cast<floatx4*>(hh + b * 512 + jj) = hf4;
        *reinterpret_cast<floatx4*>(cc + b * 512 + jj) = cf4;
      }
    }

    // Release: barrier drains vmcnt(0) (all h-stores acked at coherent point),
    // then publish this block's flag for step t.
    __syncthreads();
    if (threadIdx.x == 0) {
      __hip_atomic_store(flags + (unsigned)t * 16 + blockIdx.x, SENTINEL,
                         __ATOMIC_RELAXED, __HIP_MEMORY_SCOPE_AGENT);
    }
  }
}

extern "C" void kernel_launch(void* const* d_in, const int* in_sizes, int n_in,
                              void* d_out, int out_size, void* d_ws, size_t ws_size,
                              hipStream_t stream) {
  (void)in_sizes; (void)n_in; (void)out_size; (void)ws_size;
  const float* x   = (const float*)d_in[0];
  const float* w0w = (const float*)d_in[1];
  const float* w0b = (const float*)d_in[2];
  const float* u0w = (const float*)d_in[3];
  const float* u0b = (const float*)d_in[4];
  const float* w1w = (const float*)d_in[5];
  const float* w1b = (const float*)d_in[6];
  const float* u1w = (const float*)d_in[7];
  const float* u1b = (const float*)d_in[8];
  float* out = (float*)d_out;

  char* ws = (char*)d_ws;
  unsigned int* flags0 = (unsigned int*)ws;
  unsigned int* flags1 = (unsigned int*)(ws + 131072);
  bf16* Wb0 = (bf16*)(ws + 262144);
  bf16* Ub0 = (bf16*)(ws + 262144 + (size_t)1048576);
  bf16* Wb1 = (bf16*)(ws + 262144 + (size_t)3145728);
  bf16* Ub1 = (bf16*)(ws + 262144 + (size_t)5242880);
  bf16* wx  = (bf16*)(ws + 7602176);
  bf16* h1s = (bf16*)(ws + 7602176 + (size_t)67108864);
  bf16* h2s = (bf16*)(ws + 7602176 + (size_t)67108864 + (size_t)33554432);

  hipMemsetAsync(ws, 0, 262144, stream);   // zero both flag arrays

  // Weight conversions fp32 -> bf16.
  cvt_f32_bf16<<<512,  256, 0, stream>>>(w0w, Wb0, 524288);
  cvt_f32_bf16<<<1024, 256, 0, stream>>>(u0w, Ub0, 1048576);
  cvt_f32_bf16<<<1024, 256, 0, stream>>>(w1w, Wb1, 1048576);
  cvt_f32_bf16<<<1024, 256, 0, stream>>>(u1w, Ub1, 1048576);

  dim3 gg(1024, 8, 1);
  // Layer 0 input projection: A = x[b][t][d] fp32.
  gemm_proj<<<gg, 256, 0, stream>>>(x, nullptr, Wb0, w0b, wx, 256, 2048 * 256, 256);
  // Layer 0 recurrence.
  lstm_rec<<<NB_REC, 256, 0, stream>>>(wx, Ub0, u0b, h1s, nullptr,
                                       out + HH_OFF, out + CC_OFF, flags0);
  // Layer 1 input projection: A = h1s[t][16][512] bf16.
  gemm_proj<<<gg, 256, 0, stream>>>(nullptr, h1s, Wb1, w1b, wx, 512, 512, 8192);
  // Layer 1 recurrence (writes h2 fp32 to d_out).
  lstm_rec<<<NB_REC, 256, 0, stream>>>(wx, Ub1, u1b, h2s, out,
                                       out + HH_OFF + 4096, out + CC_OFF + 4096, flags1);
}